// Round 3
// baseline (191.881 us; speedup 1.0000x reference)
//
#include <hip/hip_runtime.h>

#define BB 64
#define SS 2048
#define DD 256

// Kernel 1: score[b,s] = dot(inputs[b,s,:], w) + bias.
// One wave (64 lanes) per (b,s) row: lane i loads float4 at offset 4i -> 1KB
// contiguous per wave, fully coalesced. Shuffle tree reduce, lane 0 writes.
__global__ __launch_bounds__(256) void score_kernel(const float* __restrict__ x,
                                                    const float* __restrict__ w,
                                                    const float* __restrict__ bias,
                                                    float* __restrict__ score) {
    const int wave = threadIdx.x >> 6;
    const int lane = threadIdx.x & 63;
    const long row = (long)blockIdx.x * 4 + wave;      // < BB*SS by grid sizing
    const float4 xv = ((const float4*)(x + row * DD))[lane];
    const float4 wv = ((const float4*)w)[lane];
    float p = xv.x * wv.x + xv.y * wv.y + xv.z * wv.z + xv.w * wv.w;
#pragma unroll
    for (int off = 32; off > 0; off >>= 1)
        p += __shfl_down(p, off, 64);
    if (lane == 0) score[row] = p + bias[0];
}

// Kernel 2: per batch row b, g[k] = score[b, guide[b,k]];
// out0[b,t] = g[t] - suffix_logsumexp(g, t); out1[b,t] = (float)guide[b,t].
// Suffix LSE via per-thread serial (8 elems) + Hillis-Steele inclusive suffix
// scan over 256 thread aggregates in (max, sumexp) form.
__global__ __launch_bounds__(256) void scan_kernel(const float* __restrict__ score,
                                                   const int* __restrict__ guide,
                                                   float* __restrict__ out) {
    const int b = blockIdx.x;
    const int j = threadIdx.x;
    const float* __restrict__ srow = score + b * SS;
    const int*   __restrict__ grow = guide + b * SS;
    const int base = j * 8;

    int   gi[8];
    float g[8], lm[8], ls[8];
#pragma unroll
    for (int i = 0; i < 8; ++i) gi[i] = grow[base + i];
#pragma unroll
    for (int i = 0; i < 8; ++i) g[i] = srow[gi[i]];   // gather, row is 8KB -> L1

    // local backward (suffix within the 8-chunk), record running (m,s) per elem
    float m = -INFINITY, s = 0.f;
#pragma unroll
    for (int i = 7; i >= 0; --i) {
        const float xv = g[i];
        const float M = fmaxf(m, xv);
        s = s * expf(m - M) + expf(xv - M);   // expf(-inf)=0 handles first step
        m = M;
        lm[i] = m; ls[i] = s;
    }

    __shared__ float sm_m[256], sm_s[256];
    sm_m[j] = m; sm_s[j] = s;
    __syncthreads();
    // inclusive suffix scan across threads (combine with thread j+off)
    for (int off = 1; off < 256; off <<= 1) {
        float nm = -INFINITY, ns = 0.f;
        if (j + off < 256) { nm = sm_m[j + off]; ns = sm_s[j + off]; }
        __syncthreads();
        const float M = fmaxf(m, nm);
        s = s * expf(m - M) + ns * expf(nm - M);  // ns=0 & expf(-inf)=0 when no neighbor
        m = M;
        sm_m[j] = m; sm_s[j] = s;
        __syncthreads();
    }
    // exclusive aggregate for this thread = inclusive of thread j+1
    const float em = (j < 255) ? sm_m[j + 1] : -INFINITY;
    const float es = (j < 255) ? sm_s[j + 1] : 0.f;

#pragma unroll
    for (int i = 0; i < 8; ++i) {
        const float M  = fmaxf(lm[i], em);
        const float Sv = ls[i] * expf(lm[i] - M) + es * expf(em - M);
        const float lse = M + logf(Sv);
        out[b * SS + base + i] = g[i] - lse;
        out[BB * SS + b * SS + base + i] = (float)gi[i];
    }
}

extern "C" void kernel_launch(void* const* d_in, const int* in_sizes, int n_in,
                              void* d_out, int out_size, void* d_ws, size_t ws_size,
                              hipStream_t stream) {
    const float* x    = (const float*)d_in[0];   // [B,S,D] f32
    const float* w    = (const float*)d_in[1];   // [D] f32
    const float* bias = (const float*)d_in[2];   // [1] f32
    const int*   gd   = (const int*)d_in[3];     // [B,S] i32
    float* out = (float*)d_out;                  // [B*S] logprobs ++ [B*S] guide-as-f32
    float* score = (float*)d_ws;                 // B*S floats = 512 KB scratch

    score_kernel<<<(BB * SS) / 4, 256, 0, stream>>>(x, w, bias, score);
    scan_kernel<<<BB, 256, 0, stream>>>(score, gd, out);
}

// Round 8
// 185.623 us; speedup vs baseline: 1.0337x; 1.0337x over previous
//
#include <hip/hip_runtime.h>

#define BB 64
#define SS 2048
#define DD 256
#define RPW 8   // rows per wave

typedef float vf4 __attribute__((ext_vector_type(4)));  // clang-native, ok for nontemporal builtins

// Kernel 1: score[b,s] = dot(inputs[b,s,:], w) + bias.
// One wave handles RPW=8 consecutive rows: 8 independent nontemporal float4
// loads in flight (1KB coalesced per load), then a shared 6-step shuffle
// reduce over all 8 partials. 1024 blocks of 256.
__global__ __launch_bounds__(256) void score_kernel(const float* __restrict__ x,
                                                    const float* __restrict__ w,
                                                    const float* __restrict__ bias,
                                                    float* __restrict__ score) {
    const int  wid  = blockIdx.x * 4 + (threadIdx.x >> 6);
    const int  lane = threadIdx.x & 63;
    const long row0 = (long)wid * RPW;
    const vf4 wv = ((const vf4*)w)[lane];
    const vf4* __restrict__ xp = (const vf4*)x + row0 * (DD / 4) + lane;

    float p[RPW];
#pragma unroll
    for (int r = 0; r < RPW; ++r) {
        const vf4 xv = __builtin_nontemporal_load(&xp[r * (DD / 4)]);
        p[r] = xv.x * wv.x + xv.y * wv.y + xv.z * wv.z + xv.w * wv.w;
    }
#pragma unroll
    for (int off = 32; off > 0; off >>= 1) {
#pragma unroll
        for (int r = 0; r < RPW; ++r) p[r] += __shfl_down(p[r], off, 64);
    }
    if (lane == 0) {
        const float b0 = bias[0];
        vf4 s0 = {p[0] + b0, p[1] + b0, p[2] + b0, p[3] + b0};
        vf4 s1 = {p[4] + b0, p[5] + b0, p[6] + b0, p[7] + b0};
        ((vf4*)(score + row0))[0] = s0;
        ((vf4*)(score + row0))[1] = s1;
    }
}

// Kernel 2: per batch row b, g[k] = score[b, guide[b,k]];
// out0[b,t] = g[t] - suffix_logsumexp(g, t); out1[b,t] = (float)guide[b,t].
// Per-thread serial suffix over 8 elems + Hillis-Steele inclusive suffix scan
// over 256 thread aggregates in (max, sumexp) form.
__global__ __launch_bounds__(256) void scan_kernel(const float* __restrict__ score,
                                                   const int* __restrict__ guide,
                                                   float* __restrict__ out) {
    const int b = blockIdx.x;
    const int j = threadIdx.x;
    const float* __restrict__ srow = score + b * SS;
    const int base = j * 8;

    const int4 ga = ((const int4*)(guide + b * SS))[j * 2];
    const int4 gb = ((const int4*)(guide + b * SS))[j * 2 + 1];
    const int gi[8] = {ga.x, ga.y, ga.z, ga.w, gb.x, gb.y, gb.z, gb.w};

    float g[8], lm[8], ls[8];
#pragma unroll
    for (int i = 0; i < 8; ++i) g[i] = srow[gi[i]];   // gather, row is 8KB -> L1/L2

    // local backward (suffix within the 8-chunk), record running (m,s) per elem
    float m = g[7], s = 1.f;
    lm[7] = m; ls[7] = s;
#pragma unroll
    for (int i = 6; i >= 0; --i) {
        const float xv = g[i];
        const float M = fmaxf(m, xv);
        s = s * expf(m - M) + expf(xv - M);
        m = M;
        lm[i] = m; ls[i] = s;
    }

    __shared__ float sm_m[256], sm_s[256];
    sm_m[j] = m; sm_s[j] = s;
    __syncthreads();
    // inclusive suffix scan across threads (combine with thread j+off)
    for (int off = 1; off < 256; off <<= 1) {
        float nm = -INFINITY, ns = 0.f;
        if (j + off < 256) { nm = sm_m[j + off]; ns = sm_s[j + off]; }
        __syncthreads();
        const float M = fmaxf(m, nm);
        s = s * expf(m - M) + ns * expf(nm - M);  // ns=0 & expf(-inf)=0 when no neighbor
        m = M;
        sm_m[j] = m; sm_s[j] = s;
        __syncthreads();
    }
    // exclusive aggregate for this thread = inclusive of thread j+1
    const float em = (j < 255) ? sm_m[j + 1] : -INFINITY;
    const float es = (j < 255) ? sm_s[j + 1] : 0.f;

    float o[8];
#pragma unroll
    for (int i = 0; i < 8; ++i) {
        const float M  = fmaxf(lm[i], em);
        const float Sv = ls[i] * expf(lm[i] - M) + es * expf(em - M);
        o[i] = g[i] - (M + logf(Sv));
    }
    float* __restrict__ o0 = out + b * SS + base;
    ((vf4*)o0)[0] = (vf4){o[0], o[1], o[2], o[3]};
    ((vf4*)o0)[1] = (vf4){o[4], o[5], o[6], o[7]};
    float* __restrict__ o1 = out + BB * SS + b * SS + base;
    ((vf4*)o1)[0] = (vf4){(float)gi[0], (float)gi[1], (float)gi[2], (float)gi[3]};
    ((vf4*)o1)[1] = (vf4){(float)gi[4], (float)gi[5], (float)gi[6], (float)gi[7]};
}

extern "C" void kernel_launch(void* const* d_in, const int* in_sizes, int n_in,
                              void* d_out, int out_size, void* d_ws, size_t ws_size,
                              hipStream_t stream) {
    const float* x    = (const float*)d_in[0];   // [B,S,D] f32
    const float* w    = (const float*)d_in[1];   // [D] f32
    const float* bias = (const float*)d_in[2];   // [1] f32
    const int*   gd   = (const int*)d_in[3];     // [B,S] i32
    float* out = (float*)d_out;                  // [B*S] logprobs ++ [B*S] guide-as-f32
    float* score = (float*)d_ws;                 // B*S floats = 512 KB scratch

    score_kernel<<<(BB * SS) / (4 * RPW), 256, 0, stream>>>(x, w, bias, score);
    scan_kernel<<<BB, 256, 0, stream>>>(score, gd, out);
}